// Round 20
// baseline (121.308 us; speedup 1.0000x reference)
//
#include <hip/hip_runtime.h>
#include <hip/hip_cooperative_groups.h>

namespace cg = cooperative_groups;

#define NN 16384      // H*W, 128x128
#define CINC 64

// ---------------------------------------------------------------------------
// k0: fold weights.
// ---------------------------------------------------------------------------
__global__ void gat_k0(const float* __restrict__ w_restore,
                       const float* __restrict__ b_gat,
                       const float* __restrict__ w_reduce,
                       const float* __restrict__ w_lin,
                       const float* __restrict__ att_src,
                       const float* __restrict__ att_dst,
                       float* __restrict__ rb, float* __restrict__ wredT,
                       float* __restrict__ S, float* __restrict__ D) {
    int t = threadIdx.x;
    if (t < 128) {
        int h = t >> 5, k = t & 31;
        float s = 0.f, d = 0.f;
        for (int c = 0; c < 32; ++c) {
            float wl = w_lin[(h * 32 + c) * 32 + k];
            s += att_src[h * 32 + c] * wl;
            d += att_dst[h * 32 + c] * wl;
        }
        S[t] = s; D[t] = d;
    } else if (t < 192) {
        int o = t - 128;
        float r = 0.f;
        for (int c = 0; c < 32; ++c) r += w_restore[o * 32 + c] * b_gat[c];
        rb[o] = r;
    }
    for (int idx = t; idx < 2048; idx += 256) {
        int k = idx & 31, c = idx >> 5;
        wredT[c * 32 + k] = w_reduce[k * 64 + c];
    }
}

// ---------------------------------------------------------------------------
// k1: reduce conv + attention logits. Strip = 64 nodes, 2048 blocks. (r12)
// ---------------------------------------------------------------------------
__global__ __launch_bounds__(256) void gat_k1(
        const float* __restrict__ x, const float* __restrict__ wredT,
        const float* __restrict__ S, const float* __restrict__ D,
        float* __restrict__ red_g, float* __restrict__ as_ws,
        float* __restrict__ ad_ws) {
    __shared__ float xs[4096];         // [c][nd] 64x64
    __shared__ float red_lds[32][64];  // [k][nd]

    int tid = threadIdx.x;
    int s = blockIdx.x;
    int b = s >> 8;
    int v0 = (s & 255) << 6;

    const float* xb = x + (size_t)b * CINC * NN + v0;
    for (int idx = tid; idx < 4096; idx += 256) {
        int c = idx >> 6, nd = idx & 63;
        xs[idx] = xb[(size_t)c * NN + nd];           // coalesced 256B rows
    }
    __syncthreads();

    int nd = tid & 63;
    int wv = __builtin_amdgcn_readfirstlane(tid >> 6);  // wave-uniform

    {
        float a0 = 0.f, a1 = 0.f, a2 = 0.f, a3 = 0.f,
              a4 = 0.f, a5 = 0.f, a6 = 0.f, a7 = 0.f;
        const float* wt = wredT + wv * 8;            // uniform base
#pragma unroll 4
        for (int c = 0; c < 64; ++c) {
            float xc = xs[c * 64 + nd];
            const float* w = wt + c * 32;            // uniform -> s_load
            a0 = fmaf(w[0], xc, a0);
            a1 = fmaf(w[1], xc, a1);
            a2 = fmaf(w[2], xc, a2);
            a3 = fmaf(w[3], xc, a3);
            a4 = fmaf(w[4], xc, a4);
            a5 = fmaf(w[5], xc, a5);
            a6 = fmaf(w[6], xc, a6);
            a7 = fmaf(w[7], xc, a7);
        }
        int k0 = wv * 8;
        float* rg = red_g + (size_t)b * 32 * NN + v0 + nd;
        red_lds[k0 + 0][nd] = a0; rg[(size_t)(k0 + 0) * NN] = a0;
        red_lds[k0 + 1][nd] = a1; rg[(size_t)(k0 + 1) * NN] = a1;
        red_lds[k0 + 2][nd] = a2; rg[(size_t)(k0 + 2) * NN] = a2;
        red_lds[k0 + 3][nd] = a3; rg[(size_t)(k0 + 3) * NN] = a3;
        red_lds[k0 + 4][nd] = a4; rg[(size_t)(k0 + 4) * NN] = a4;
        red_lds[k0 + 5][nd] = a5; rg[(size_t)(k0 + 5) * NN] = a5;
        red_lds[k0 + 6][nd] = a6; rg[(size_t)(k0 + 6) * NN] = a6;
        red_lds[k0 + 7][nd] = a7; rg[(size_t)(k0 + 7) * NN] = a7;
    }
    __syncthreads();

    {
        float rv[32];
#pragma unroll
        for (int k = 0; k < 32; ++k) rv[k] = red_lds[k][nd];
        const float* sp = S + wv * 32;               // uniform base
        const float* dp = D + wv * 32;
        float pas = 0.f, pad_ = 0.f;
#pragma unroll
        for (int k = 0; k < 32; ++k) {
            pas  = fmaf(sp[k], rv[k], pas);
            pad_ = fmaf(dp[k], rv[k], pad_);
        }
        as_ws[((size_t)b * 4 + wv) * NN + v0 + nd] = pas;
        ad_ws[((size_t)b * 4 + wv) * NN + v0 + nd] = pad_;
    }
}

// ---------------------------------------------------------------------------
// shared strip pipeline (r18 structure): alphas -> k-range stencil -> fold
// -> head-reduce -> restore + residual; pre-BN parked in region LDS;
// BN partial sums accumulated into stat_lds.
// ---------------------------------------------------------------------------
__device__ __forceinline__ void process_strip(
        int strip, int tid, float* region, float* stat_lds, bool first,
        const float* __restrict__ x, const float* __restrict__ w_lin,
        const float* __restrict__ w_restore, const float* __restrict__ rb,
        const float* __restrict__ red_g, const float* __restrict__ as_ws,
        const float* __restrict__ ad_ws) {
    float (*gp)[8][64] = reinterpret_cast<float (*)[8][64]>(region);
    float (*gout)[64]  = reinterpret_cast<float (*)[64]>(region + 2048);
    float* lds_out     = region;

    int b = strip >> 8;
    int v0 = (strip & 255) << 6;
    int nd = tid & 63;
    int wv = __builtin_amdgcn_readfirstlane(tid >> 6);
    int v = v0 + nd;
    int i = v >> 7, j = v & 127;

    int un0 = v;
    int un1 = i > 0   ? v - 128 : v;
    int un2 = i < 127 ? v + 128 : v;
    int un3 = j > 0   ? v - 1   : v;
    int un4 = j < 127 ? v + 1   : v;

    float al[4][5];
#pragma unroll
    for (int h = 0; h < 4; ++h) {
        const float* asp = as_ws + ((size_t)b * 4 + h) * NN;
        float adv = ad_ws[((size_t)b * 4 + h) * NN + v];
        float e0 = asp[un0] + adv, e1 = asp[un1] + adv, e2 = asp[un2] + adv,
              e3 = asp[un3] + adv, e4 = asp[un4] + adv;
        e0 = e0 > 0.f ? e0 : 0.2f * e0;
        e1 = e1 > 0.f ? e1 : 0.2f * e1;
        e2 = e2 > 0.f ? e2 : 0.2f * e2;
        e3 = e3 > 0.f ? e3 : 0.2f * e3;
        e4 = e4 > 0.f ? e4 : 0.2f * e4;
        e1 += i > 0   ? 0.f : -1e30f;
        e2 += i < 127 ? 0.f : -1e30f;
        e3 += j > 0   ? 0.f : -1e30f;
        e4 += j < 127 ? 0.f : -1e30f;
        float m = fmaxf(fmaxf(fmaxf(e0, e1), fmaxf(e2, e3)), e4);
        e0 = __expf(e0 - m); e1 = __expf(e1 - m); e2 = __expf(e2 - m);
        e3 = __expf(e3 - m); e4 = __expf(e4 - m);
        float sc = 0.25f / (e0 + e1 + e2 + e3 + e4);
        al[h][0] = e0 * sc; al[h][1] = e1 * sc; al[h][2] = e2 * sc;
        al[h][3] = e3 * sc; al[h][4] = e4 * sc;
    }

    float gpart[32];
#pragma unroll
    for (int c = 0; c < 32; ++c) gpart[c] = 0.f;

    const float* rp = red_g + (size_t)b * 32 * NN + (size_t)(wv * 8) * NN;
    const float* wl = w_lin;
#pragma unroll 1
    for (int kc = 0; kc < 4; ++kc) {
        const float* rk0 = rp + (size_t)(kc * 2) * NN;
        const float* rk1 = rk0 + NN;
        float t00 = rk0[un0], t01 = rk0[un1], t02 = rk0[un2],
              t03 = rk0[un3], t04 = rk0[un4];
        float t10 = rk1[un0], t11 = rk1[un1], t12 = rk1[un2],
              t13 = rk1[un3], t14 = rk1[un4];
        float r0[4], r1[4];
#pragma unroll
        for (int h = 0; h < 4; ++h) {
            r0[h] = al[h][0] * t00 + al[h][1] * t01 + al[h][2] * t02 +
                    al[h][3] * t03 + al[h][4] * t04;
            r1[h] = al[h][0] * t10 + al[h][1] * t11 + al[h][2] * t12 +
                    al[h][3] * t13 + al[h][4] * t14;
        }
#pragma unroll
        for (int c = 0; c < 32; ++c) {
#pragma unroll
            for (int h = 0; h < 4; ++h) {
                const float* wk = wl + (h * 32 + c) * 32 + wv * 8 + kc * 2;
                gpart[c] += wk[0] * r0[h] + wk[1] * r1[h];
            }
        }
    }

    __syncthreads();   // region free (prev contents consumed)
#pragma unroll
    for (int q = 0; q < 4; ++q) {
#pragma unroll
        for (int cq = 0; cq < 8; ++cq) gp[wv][cq][nd] = gpart[q * 8 + cq];
        __syncthreads();
#pragma unroll
        for (int t2 = 0; t2 < 2; ++t2) {
            int cq = wv * 2 + t2;
            gout[q * 8 + cq][nd] = gp[0][cq][nd] + gp[1][cq][nd] +
                                   gp[2][cq][nd] + gp[3][cq][nd];
        }
        __syncthreads();
    }

    {
        float gv[32];
#pragma unroll
        for (int c = 0; c < 32; ++c) gv[c] = gout[c][nd];
        __syncthreads();               // gout consumed; lds_out may overwrite
        const float* xb = x + (size_t)b * CINC * NN + v0 + nd;
        const float* wr_h = w_restore + (size_t)wv * 16 * 32;
#pragma unroll 2
        for (int o16 = 0; o16 < 16; ++o16) {
            int o = wv * 16 + o16;
            const float* wr = wr_h + o16 * 32;
            float acc = rb[o];
#pragma unroll
            for (int c = 0; c < 32; ++c)
                acc = fmaf(wr[c], gv[c], acc);
            acc += xb[(size_t)o * NN];               // residual
            lds_out[o16 * 256 + tid] = acc;          // park pre-BN
            float r1 = acc, r2 = acc * acc;
#pragma unroll
            for (int off = 32; off > 0; off >>= 1) {
                r1 += __shfl_xor(r1, off, 64);
                r2 += __shfl_xor(r2, off, 64);
            }
            if (nd == 0) {
                if (first) { stat_lds[o] = r1; stat_lds[64 + o] = r2; }
                else       { stat_lds[o] += r1; stat_lds[64 + o] += r2; }
            }
        }
    }
}

// ---------------------------------------------------------------------------
// k2f: FUSED k2+k2b+k3, cooperative, 1024 blocks x 2 strips (4 blocks/CU
//      co-residency with slack: LDS 4x33KB=132/160KB, VGPR cap 128 vs ~50
//      used, wave slots 16/32). Cross-block data (part/stats) via
//      agent-scope atomics (XCD L2s not coherent).
// ---------------------------------------------------------------------------
__global__ __launch_bounds__(256, 4) void gat_k2f(
        const float* __restrict__ x, const float* __restrict__ w_lin,
        const float* __restrict__ w_restore, const float* __restrict__ rb,
        const float* __restrict__ red_g, const float* __restrict__ as_ws,
        const float* __restrict__ ad_ws, const float* __restrict__ gamma,
        const float* __restrict__ beta, float* __restrict__ outp,
        float* __restrict__ part, float* __restrict__ stats) {
    __shared__ float regionA[4096];
    __shared__ float regionB[4096];
    __shared__ float stat_lds[128];
    __shared__ float red4[4];

    cg::grid_group grid = cg::this_grid();

    int tid = threadIdx.x;
    int bid = blockIdx.x;
    int nd = tid & 63;
    int wv = __builtin_amdgcn_readfirstlane(tid >> 6);

    process_strip(bid * 2 + 0, tid, regionA, stat_lds, true,
                  x, w_lin, w_restore, rb, red_g, as_ws, ad_ws);
    __syncthreads();
    process_strip(bid * 2 + 1, tid, regionB, stat_lds, false,
                  x, w_lin, w_restore, rb, red_g, as_ws, ad_ws);
    __syncthreads();
    if (tid < 128)
        __hip_atomic_store(&part[(size_t)bid * 128 + tid], stat_lds[tid],
                           __ATOMIC_RELAXED, __HIP_MEMORY_SCOPE_AGENT);

    grid.sync();

    if (bid < 128) {
        float acc = 0.f;
        for (int q = tid; q < 1024; q += 256)
            acc += __hip_atomic_load(&part[(size_t)q * 128 + bid],
                                     __ATOMIC_RELAXED,
                                     __HIP_MEMORY_SCOPE_AGENT);
#pragma unroll
        for (int off = 32; off > 0; off >>= 1) acc += __shfl_xor(acc, off, 64);
        if (nd == 0) red4[wv] = acc;
        __syncthreads();
        if (tid == 0)
            __hip_atomic_store(&stats[bid], red4[0] + red4[1] + red4[2] + red4[3],
                               __ATOMIC_RELAXED, __HIP_MEMORY_SCOPE_AGENT);
    }

    grid.sync();

    // ---- BN + ReLU from LDS, single output write, both strips ----
    const float cnt_inv = 1.f / 131072.f;            // B*H*W
#pragma unroll
    for (int sid = 0; sid < 2; ++sid) {
        int strip = bid * 2 + sid;
        int b = strip >> 8;
        int v0 = (strip & 255) << 6;
        float* region = sid ? regionB : regionA;
        float* ob = outp + (size_t)b * CINC * NN + v0 + nd;
#pragma unroll 2
        for (int o16 = 0; o16 < 16; ++o16) {
            int o = wv * 16 + o16;
            float s1 = __hip_atomic_load(&stats[o], __ATOMIC_RELAXED,
                                         __HIP_MEMORY_SCOPE_AGENT);
            float s2 = __hip_atomic_load(&stats[64 + o], __ATOMIC_RELAXED,
                                         __HIP_MEMORY_SCOPE_AGENT);
            float mean = s1 * cnt_inv;
            float var = s2 * cnt_inv - mean * mean;
            float inv = rsqrtf(var + 1e-5f);
            float sc = gamma[o] * inv;
            float sh = beta[o] - mean * sc;
            float val = region[o16 * 256 + tid];
            ob[(size_t)o * NN] = fmaxf(val * sc + sh, 0.f);
        }
    }
}

// ---------------------------------------------------------------------------
// FALLBACK path (r18, proven 103us): k2 + k2b + k3
// ---------------------------------------------------------------------------
__global__ __launch_bounds__(256) void gat_k2(
        const float* __restrict__ x, const float* __restrict__ w_lin,
        const float* __restrict__ w_restore, const float* __restrict__ rb,
        const float* __restrict__ red_g, const float* __restrict__ as_ws,
        const float* __restrict__ ad_ws, float* __restrict__ outp,
        float* __restrict__ part) {
    __shared__ float region[4096];
    __shared__ float stat_lds[128];
    int tid = threadIdx.x;
    int s = blockIdx.x;
    process_strip(s, tid, region, stat_lds, true,
                  x, w_lin, w_restore, rb, red_g, as_ws, ad_ws);
    __syncthreads();
    // write pre-BN out from LDS (k3 will re-read)
    int nd = tid & 63;
    int wv = __builtin_amdgcn_readfirstlane(tid >> 6);
    int b = s >> 8;
    int v0 = (s & 255) << 6;
    float* ob = outp + (size_t)b * CINC * NN + v0 + nd;
#pragma unroll 2
    for (int o16 = 0; o16 < 16; ++o16) {
        int o = wv * 16 + o16;
        ob[(size_t)o * NN] = region[o16 * 256 + tid];
    }
    if (tid < 128) part[(size_t)s * 128 + tid] = stat_lds[tid];
}

__global__ __launch_bounds__(256) void gat_k2b(
        const float* __restrict__ part, float* __restrict__ stats) {
    __shared__ float red[4];
    int jj = blockIdx.x;
    int tid = threadIdx.x;
    float acc = 0.f;
    for (int s = tid; s < 2048; s += 256) acc += part[(size_t)s * 128 + jj];
#pragma unroll
    for (int off = 32; off > 0; off >>= 1) acc += __shfl_xor(acc, off, 64);
    int wv = tid >> 6, lane = tid & 63;
    if (lane == 0) red[wv] = acc;
    __syncthreads();
    if (tid == 0) stats[jj] = red[0] + red[1] + red[2] + red[3];
}

__global__ __launch_bounds__(256) void gat_k3(
        float* __restrict__ out, const float* __restrict__ stats,
        const float* __restrict__ gamma, const float* __restrict__ beta) {
    int f = blockIdx.x * 256 + threadIdx.x;
    int e = f * 4;
    int c = (e >> 14) & 63;
    const float cnt_inv = 1.f / 131072.f;
    float mean = stats[c] * cnt_inv;
    float var = stats[64 + c] * cnt_inv - mean * mean;
    float inv = rsqrtf(var + 1e-5f);
    float sc = gamma[c] * inv;
    float sh = beta[c] - mean * sc;
    float4 vv = reinterpret_cast<float4*>(out)[f];
    vv.x = fmaxf(vv.x * sc + sh, 0.f);
    vv.y = fmaxf(vv.y * sc + sh, 0.f);
    vv.z = fmaxf(vv.z * sc + sh, 0.f);
    vv.w = fmaxf(vv.w * sc + sh, 0.f);
    reinterpret_cast<float4*>(out)[f] = vv;
}

// ---------------------------------------------------------------------------
extern "C" void kernel_launch(void* const* d_in, const int* in_sizes, int n_in,
                              void* d_out, int out_size, void* d_ws, size_t ws_size,
                              hipStream_t stream) {
    const float* x         = (const float*)d_in[0];
    const float* w_reduce  = (const float*)d_in[1];
    const float* w_lin     = (const float*)d_in[2];
    const float* att_src   = (const float*)d_in[3];
    const float* att_dst   = (const float*)d_in[4];
    const float* b_gat     = (const float*)d_in[5];
    const float* w_restore = (const float*)d_in[6];
    const float* bn_gamma  = (const float*)d_in[7];
    const float* bn_beta   = (const float*)d_in[8];

    float* ws     = (float*)d_ws;
    float* red_g  = ws;                       // 8*32*16384 = 4,194,304
    float* as_ws  = red_g + 4194304;          // 524,288
    float* ad_ws  = as_ws + 524288;           // 524,288
    float* Sf     = ad_ws + 524288;           // 128
    float* Df     = Sf + 128;                 // 128
    float* rbf    = Df + 128;                 // 64
    float* wredT  = rbf + 64;                 // 2048
    float* stats  = wredT + 2048;             // 128
    float* part   = stats + 128;              // up to 2048*128

    float* outp = (float*)d_out;

    gat_k0<<<1, 256, 0, stream>>>(w_restore, b_gat, w_reduce, w_lin,
                                  att_src, att_dst, rbf, wredT, Sf, Df);
    gat_k1<<<2048, 256, 0, stream>>>(x, wredT, Sf, Df, red_g, as_ws, ad_ws);

    // capture-safe host queries (no stream ops) decide the path
    int dev = 0;
    hipGetDevice(&dev);
    int coop = 0, ncu = 0, maxB = 0;
    hipDeviceGetAttribute(&coop, hipDeviceAttributeCooperativeLaunch, dev);
    hipDeviceGetAttribute(&ncu, hipDeviceAttributeMultiprocessorCount, dev);
    hipOccupancyMaxActiveBlocksPerMultiprocessor(&maxB, (const void*)gat_k2f,
                                                 256, 0);
    bool useCoop = coop && ((long)maxB * (long)ncu >= 1024L);

    if (useCoop) {
        void* args[] = { (void*)&x, (void*)&w_lin, (void*)&w_restore,
                         (void*)&rbf, (void*)&red_g, (void*)&as_ws,
                         (void*)&ad_ws, (void*)&bn_gamma, (void*)&bn_beta,
                         (void*)&outp, (void*)&part, (void*)&stats };
        hipLaunchCooperativeKernel((void*)gat_k2f, dim3(1024), dim3(256),
                                   args, 0, stream);
    } else {
        gat_k2<<<2048, 256, 0, stream>>>(x, w_lin, w_restore, rbf, red_g,
                                         as_ws, ad_ws, outp, part);
        gat_k2b<<<128, 256, 0, stream>>>(part, stats);
        gat_k3<<<8192, 256, 0, stream>>>(outp, stats, bn_gamma, bn_beta);
    }
}